// Round 7
// baseline (111198.657 us; speedup 1.0000x reference)
//
#include <hip/hip_runtime.h>
#include <hip/hip_cooperative_groups.h>
#include <math.h>

namespace cg = cooperative_groups;

#define HD 1024
#define BB 50
#define SS 457
#define TT 32
#define VV 27

#define SSTR 68
#define WSTR 68

#define SIGM(v) (1.f / (1.f + expf(-(v))))

// ===========================================================================
// Persistent cooperative encoder: 256 WGs x 1024 threads, 458 phases.
// Phase p: L0 computes h0[p] = GRU(x_p, h0[p-1]); L1 computes h1[p-1] =
// GRU(h0[p-1], h1[p-2]) and writes enc[p-1]. One grid.sync() per phase.
// WG owns 4 j-columns (j = blockIdx.x*4 .. +3)  [256*4 = 1024 exactly —
// round-6 bug was 12 cols/WG with 256 WGs -> OOB weight reads].
// Waves: wv = (rg 0..3 = j-column) x (kh 0..3 = k-quarter);
// lane = (tx 0..3 sub-k of 4) x (ty 0..15 batch-quad).
// Double-buffered LDS windows (64 k x 64 b) with prefetch-during-compute.
// ===========================================================================
struct EncArgs {
  const float *x, *Wih0, *Whh0, *bih0, *bhh0, *Wih1, *Whh1, *bih1, *bhh1;
  float *h0a, *h0b2, *h1a, *h1b2, *enc;
};

#define DOT4(A, wq) do { \
  A[0] = fmaf(wq.x, s0.x, A[0]); A[1] = fmaf(wq.x, s0.y, A[1]); \
  A[2] = fmaf(wq.x, s0.z, A[2]); A[3] = fmaf(wq.x, s0.w, A[3]); \
  A[0] = fmaf(wq.y, s1.x, A[0]); A[1] = fmaf(wq.y, s1.y, A[1]); \
  A[2] = fmaf(wq.y, s1.z, A[2]); A[3] = fmaf(wq.y, s1.w, A[3]); \
  A[0] = fmaf(wq.z, s2.x, A[0]); A[1] = fmaf(wq.z, s2.y, A[1]); \
  A[2] = fmaf(wq.z, s2.z, A[2]); A[3] = fmaf(wq.z, s2.w, A[3]); \
  A[0] = fmaf(wq.w, s3.x, A[0]); A[1] = fmaf(wq.w, s3.y, A[1]); \
  A[2] = fmaf(wq.w, s3.z, A[2]); A[3] = fmaf(wq.w, s3.w, A[3]); } while (0)

__global__ __launch_bounds__(1024) void enc_persistent(EncArgs A)
{
  __shared__ __align__(16) float Sk[2][64][SSTR];   // 34.0 KB
  __shared__ __align__(16) float Wt[2][12][WSTR];   //  6.4 KB
  __shared__ __align__(16) float part[2][16][64];   //  8.0 KB

  const int tid = threadIdx.x;
  const int wj0 = blockIdx.x * 4;          // 4 columns per WG, <= 1020
  const int lane = tid & 63;
  const int wv = tid >> 6;
  const int rg = wv & 3;                   // which j-column of the 4
  const int kh = wv >> 2;                  // k-quarter
  const int tx = lane & 3;
  const int ty = lane >> 2;
  const int sb = tid >> 4;                 // Sk staging batch row 0..63
  const int sbc = sb < BB ? sb : BB - 1;
  const int sf4 = tid & 15;                // float4 index along k
  const int wr = tid >> 4;                 // Wt staging row 0..11 (tid<192)
  const int wjl = wr & 3;                  // j within group
  const int wg = wr >> 2;                  // gate 0..2
  const int wrow = wg * 1024 + wj0 + wjl;  // row in (3072, K) weights, <=3071

  cg::grid_group grid = cg::this_grid();

  float* h0buf[2] = { A.h0a, A.h0b2 };
  float* h1buf[2] = { A.h1a, A.h1b2 };

  auto do_pass = [&](const float* sA, const float* WA,
                     const float* sB, const float* WB,
                     int nwin, int dual) {
    float aR[4], aZ[4], aNi[4], aNh[4];
#pragma unroll
    for (int bi = 0; bi < 4; ++bi) {
      aR[bi] = 0.f; aZ[bi] = 0.f; aNi[bi] = 0.f; aNh[bi] = 0.f;
    }

    // prologue: stage window 0 into buf 0
    {
      float4 hv = *(const float4*)(sA + (size_t)sbc * 1024 + (sf4 << 2));
      float4 wvv = make_float4(0.f, 0.f, 0.f, 0.f);
      if (tid < 192) wvv = *(const float4*)(WA + (size_t)wrow * 1024 + (sf4 << 2));
      const int k4 = sf4 << 2;
      Sk[0][k4 + 0][sb] = hv.x; Sk[0][k4 + 1][sb] = hv.y;
      Sk[0][k4 + 2][sb] = hv.z; Sk[0][k4 + 3][sb] = hv.w;
      if (tid < 192) *(float4*)&Wt[0][wr][k4] = wvv;
    }
    __syncthreads();

    for (int win = 0; win < nwin; ++win) {
      const int buf = win & 1;
      const int nxt = win + 1;
      float4 hv2 = make_float4(0.f, 0.f, 0.f, 0.f);
      float4 wv2 = make_float4(0.f, 0.f, 0.f, 0.f);
      if (nxt < nwin) {   // issue next-window loads; latency hides under FMAs
        const float* hs; const float* Wm; int ko;
        if (dual && nxt >= 16) { hs = sB; Wm = WB; ko = (nxt - 16) << 6; }
        else                   { hs = sA; Wm = WA; ko = nxt << 6; }
        hv2 = *(const float4*)(hs + (size_t)sbc * 1024 + ko + (sf4 << 2));
        if (tid < 192) wv2 = *(const float4*)(Wm + (size_t)wrow * 1024 + ko + (sf4 << 2));
      }
      // compute current window from LDS
      const int kk = (kh << 4) + (tx << 2);
      const float4 s0 = *(const float4*)&Sk[buf][kk + 0][ty << 2];
      const float4 s1 = *(const float4*)&Sk[buf][kk + 1][ty << 2];
      const float4 s2 = *(const float4*)&Sk[buf][kk + 2][ty << 2];
      const float4 s3 = *(const float4*)&Sk[buf][kk + 3][ty << 2];
      const int useNi = dual && (win < 16);
      {
        const float4 w0 = *(const float4*)&Wt[buf][rg][kk];
        const float4 w1 = *(const float4*)&Wt[buf][4 + rg][kk];
        const float4 w2 = *(const float4*)&Wt[buf][8 + rg][kk];
        DOT4(aR, w0);
        DOT4(aZ, w1);
        if (useNi) { DOT4(aNi, w2); } else { DOT4(aNh, w2); }
      }
      // commit next window into other buffer
      if (nxt < nwin) {
        const int nb = nxt & 1;
        const int k4 = sf4 << 2;
        Sk[nb][k4 + 0][sb] = hv2.x; Sk[nb][k4 + 1][sb] = hv2.y;
        Sk[nb][k4 + 2][sb] = hv2.z; Sk[nb][k4 + 3][sb] = hv2.w;
        if (tid < 192) *(float4*)&Wt[nb][wr][k4] = wv2;
      }
      __syncthreads();
    }

    // reduce over tx (sub-k) within wave
#pragma unroll
    for (int bi = 0; bi < 4; ++bi) {
      aR[bi]  += __shfl_xor(aR[bi], 1, 64);
      aR[bi]  += __shfl_xor(aR[bi], 2, 64);
      aZ[bi]  += __shfl_xor(aZ[bi], 1, 64);
      aZ[bi]  += __shfl_xor(aZ[bi], 2, 64);
      aNi[bi] += __shfl_xor(aNi[bi], 1, 64);
      aNi[bi] += __shfl_xor(aNi[bi], 2, 64);
      aNh[bi] += __shfl_xor(aNh[bi], 1, 64);
      aNh[bi] += __shfl_xor(aNh[bi], 2, 64);
    }
    // kh-reduction via two slabs, deterministic order
    if (tx == 0 && (kh & 1) == 0) {
      const int pr = rg << 2;
      *(float4*)&part[kh >> 1][pr + 0][ty << 2] = make_float4(aR[0], aR[1], aR[2], aR[3]);
      *(float4*)&part[kh >> 1][pr + 1][ty << 2] = make_float4(aZ[0], aZ[1], aZ[2], aZ[3]);
      *(float4*)&part[kh >> 1][pr + 2][ty << 2] = make_float4(aNi[0], aNi[1], aNi[2], aNi[3]);
      *(float4*)&part[kh >> 1][pr + 3][ty << 2] = make_float4(aNh[0], aNh[1], aNh[2], aNh[3]);
    }
    __syncthreads();
    if (tx == 0 && (kh & 1) == 1) {
      const int pr = rg << 2;
      float4* q0 = (float4*)&part[kh >> 1][pr + 0][ty << 2];
      float4* q1 = (float4*)&part[kh >> 1][pr + 1][ty << 2];
      float4* q2 = (float4*)&part[kh >> 1][pr + 2][ty << 2];
      float4* q3 = (float4*)&part[kh >> 1][pr + 3][ty << 2];
      float4 v0 = *q0; v0.x += aR[0];  v0.y += aR[1];  v0.z += aR[2];  v0.w += aR[3];  *q0 = v0;
      float4 v1 = *q1; v1.x += aZ[0];  v1.y += aZ[1];  v1.z += aZ[2];  v1.w += aZ[3];  *q1 = v1;
      float4 v2 = *q2; v2.x += aNi[0]; v2.y += aNi[1]; v2.z += aNi[2]; v2.w += aNi[3]; *q2 = v2;
      float4 v3 = *q3; v3.x += aNh[0]; v3.y += aNh[1]; v3.z += aNh[2]; v3.w += aNh[3]; *q3 = v3;
    }
    __syncthreads();
  };

  for (int p = 0; p <= 457; ++p) {
    const float* h0r = h0buf[(p + 1) & 1];
    float*       h0w = h0buf[p & 1];
    const float* h1r = h1buf[p & 1];
    float*       h1w = h1buf[(p + 1) & 1];

    if (p < 457) {           // L0: h0[p] = GRU(x_p, h0[p-1])
      do_pass(h0r, A.Whh0, nullptr, nullptr, 16, 0);
      if (tid < 200) {
        const int jl = tid / 50, b = tid - jl * 50;
        const int j = wj0 + jl;
        const int pr = jl << 2;
        const float dR  = part[0][pr + 0][b] + part[1][pr + 0][b];
        const float dZ  = part[0][pr + 1][b] + part[1][pr + 1][b];
        const float dNh = part[0][pr + 3][b] + part[1][pr + 3][b];
        const float x0 = A.x[b * 914 + p];
        const float x1 = A.x[b * 914 + 457 + p];
        const float pf = (float)p;
        const float* w3r = A.Wih0 + (size_t)j * 3;
        const float* w3z = A.Wih0 + (size_t)(1024 + j) * 3;
        const float* w3n = A.Wih0 + (size_t)(2048 + j) * 3;
        const float gir = w3r[0]*x0 + w3r[1]*x1 + w3r[2]*pf + A.bih0[j];
        const float giz = w3z[0]*x0 + w3z[1]*x1 + w3z[2]*pf + A.bih0[1024 + j];
        const float gin = w3n[0]*x0 + w3n[1]*x1 + w3n[2]*pf + A.bih0[2048 + j];
        const float rr = SIGM(gir + dR + A.bhh0[j]);
        const float zz = SIGM(giz + dZ + A.bhh0[1024 + j]);
        const float nn = tanhf(gin + rr * (dNh + A.bhh0[2048 + j]));
        const float hv0 = h0r[b * 1024 + j];
        h0w[b * 1024 + j] = (1.f - zz) * nn + zz * hv0;
      }
      __syncthreads();
    }
    if (p > 0) {             // L1: h1[p-1] = GRU(h0[p-1], h1[p-2]) -> enc[p-1]
      do_pass(h0r, A.Wih1, h1r, A.Whh1, 32, 1);
      if (tid < 200) {
        const int jl = tid / 50, b = tid - jl * 50;
        const int j = wj0 + jl;
        const int pr = jl << 2;
        const float dR  = part[0][pr + 0][b] + part[1][pr + 0][b];
        const float dZ  = part[0][pr + 1][b] + part[1][pr + 1][b];
        const float dNi = part[0][pr + 2][b] + part[1][pr + 2][b];
        const float dNh = part[0][pr + 3][b] + part[1][pr + 3][b];
        const float rr = SIGM(dR + A.bih1[j] + A.bhh1[j]);
        const float zz = SIGM(dZ + A.bih1[1024 + j] + A.bhh1[1024 + j]);
        const float nn = tanhf(dNi + A.bih1[2048 + j] + rr * (dNh + A.bhh1[2048 + j]));
        const float hv1 = h1r[b * 1024 + j];
        const float h2 = (1.f - zz) * nn + zz * hv1;
        h1w[b * 1024 + j] = h2;
        A.enc[(size_t)(p - 1) * (BB * HD) + b * 1024 + j] = h2;
      }
      __syncthreads();
    }
    grid.sync();
  }
}

// ===========================================================================
// Decoder kernels (unchanged from round 5, which passed)
// ===========================================================================
enum { G_ENC0 = 0, G_GRU = 1, G_SCR = 2, G_SCRGATE = 3, G_RELU = 4 };

struct Role {
  const float* srcA; const float* srcB;
  const float* Wa;   const float* Wb;
  const float* bih;  const float* bhh;
  const float* hv;   const float* scr;
  float* out; float* out2; float* scrw;
  int strA, strB, wstrA, K, gate, rowsLinear, gatherA, nsA, nsB;
};

__global__ __launch_bounds__(256) void fused_gemm(
    Role r0, Role r1, int split, int skipRole, int p,
    const float* __restrict__ x, const float* __restrict__ Wih0,
    const float* __restrict__ emb, const int* __restrict__ tok)
{
  __shared__ __align__(16) float Sk[64][SSTR];
  __shared__ __align__(16) float Wt[12][WSTR];
  __shared__ __align__(16) float part[4][16][4][4][4];

  const int blk = blockIdx.x;
  const int roleId = split ? (blk & 1) : 0;
  if (roleId == skipRole) return;
  const Role& R = roleId ? r1 : r0;
  const int bi2 = split ? (blk >> 1) : blk;
  const int j0 = bi2 * (R.rowsLinear ? 12 : 4);

  const int tid = threadIdx.x;
  const int tx = tid & 3;
  const int ty = (tid >> 2) & 15;
  const int kh = tid >> 6;

  float aR[4] = {0,0,0,0}, aZ[4] = {0,0,0,0}, aN2[4] = {0,0,0,0}, aN3[4] = {0,0,0,0};

  const int nit = R.K >> 6;

  for (int it = 0; it < nit; ++it) {
    const int kw = it << 6;
    const bool second = (R.srcB != nullptr) && (kw >= 1024);
    const int kloc = second ? (kw - 1024) : kw;

    float4 sv[4];
#pragma unroll
    for (int u = 0; u < 4; ++u) {
      int e = tid + (u << 8);
      int b = e >> 4, f4 = e & 15;
      int bc = b < BB ? b : BB - 1;
      const float* rp;
      if (second)         rp = R.srcB + (size_t)bc * R.strB + kloc;
      else if (R.gatherA) rp = emb + (size_t)tok[bc] * HD + kw;
      else                rp = R.srcA + (size_t)bc * R.strA + kw;
      sv[u] = *(const float4*)(rp + (f4 << 2));
    }
    float4 wvq = make_float4(0.f, 0.f, 0.f, 0.f);
    if (tid < 192) {
      int r = tid >> 4, f4 = tid & 15;
      int wrow;
      if (R.rowsLinear) { int j = j0 + r; wrow = j < 1024 ? j : 1023; }
      else { int g = r >> 2, jj = r & 3; int j = j0 + jj; if (j > 1023) j = 1023;
             wrow = g * 1024 + j; }
      const float* wp = second ? (R.Wb + (size_t)wrow * 1024 + kloc)
                               : (R.Wa + (size_t)wrow * R.wstrA + kw);
      wvq = *(const float4*)(wp + (f4 << 2));
    }

    __syncthreads();
#pragma unroll
    for (int u = 0; u < 4; ++u) {
      int e = tid + (u << 8);
      int b = e >> 4, f4 = e & 15;
      int k = f4 << 2;
      Sk[k + 0][b] = sv[u].x;
      Sk[k + 1][b] = sv[u].y;
      Sk[k + 2][b] = sv[u].z;
      Sk[k + 3][b] = sv[u].w;
    }
    if (tid < 192) {
      int r = tid >> 4, f4 = tid & 15;
      *(float4*)&Wt[r][f4 << 2] = wvq;
    }
    __syncthreads();

    const bool ns2 = second ? (R.nsB == 2) : (R.nsA == 2);
#define FMA4(A, wc, s) { A[0] = fmaf(wc, s.x, A[0]); A[1] = fmaf(wc, s.y, A[1]); \
                         A[2] = fmaf(wc, s.z, A[2]); A[3] = fmaf(wc, s.w, A[3]); }
#define CBLOCK(AN) \
    _Pragma("unroll") \
    for (int k4 = 0; k4 < 4; ++k4) { \
      const int kk = (kh << 4) + (k4 << 2); \
      float4 w0 = *(const float4*)&Wt[tx][kk]; \
      float4 w1 = *(const float4*)&Wt[4 + tx][kk]; \
      float4 w2 = *(const float4*)&Wt[8 + tx][kk]; \
      float4 s0 = *(const float4*)&Sk[kk + 0][ty << 2]; \
      float4 s1 = *(const float4*)&Sk[kk + 1][ty << 2]; \
      float4 s2 = *(const float4*)&Sk[kk + 2][ty << 2]; \
      float4 s3 = *(const float4*)&Sk[kk + 3][ty << 2]; \
      FMA4(aR, w0.x, s0) FMA4(aR, w0.y, s1) FMA4(aR, w0.z, s2) FMA4(aR, w0.w, s3) \
      FMA4(aZ, w1.x, s0) FMA4(aZ, w1.y, s1) FMA4(aZ, w1.z, s2) FMA4(aZ, w1.w, s3) \
      FMA4(AN, w2.x, s0) FMA4(AN, w2.y, s1) FMA4(AN, w2.z, s2) FMA4(AN, w2.w, s3) \
    }
    if (ns2) { CBLOCK(aN2) } else { CBLOCK(aN3) }
    __syncthreads();
  }

  *(float4*)&part[kh][ty][tx][0][0] = make_float4(aR[0], aR[1], aR[2], aR[3]);
  *(float4*)&part[kh][ty][tx][1][0] = make_float4(aZ[0], aZ[1], aZ[2], aZ[3]);
  *(float4*)&part[kh][ty][tx][2][0] = make_float4(aN2[0], aN2[1], aN2[2], aN2[3]);
  *(float4*)&part[kh][ty][tx][3][0] = make_float4(aN3[0], aN3[1], aN3[2], aN3[3]);
  __syncthreads();

  if (tid < 200) {
    int b = tid >> 2, jj = tid & 3;
    int py = b >> 2, pi = b & 3;
    float d0 = 0.f, d1 = 0.f, d2 = 0.f, d3 = 0.f;
#pragma unroll
    for (int q = 0; q < 4; ++q) {
      d0 += part[q][py][jj][0][pi];
      d1 += part[q][py][jj][1][pi];
      d2 += part[q][py][jj][2][pi];
      d3 += part[q][py][jj][3][pi];
    }
    if (R.gate == G_ENC0) {
      int j = j0 + jj;
      float x0 = x[b * 914 + p], x1 = x[b * 914 + 457 + p], pf = (float)p;
      const float* w3r = Wih0 + (size_t)j * 3;
      const float* w3z = Wih0 + (size_t)(1024 + j) * 3;
      const float* w3n = Wih0 + (size_t)(2048 + j) * 3;
      float gir = w3r[0]*x0 + w3r[1]*x1 + w3r[2]*pf + R.bih[j];
      float giz = w3z[0]*x0 + w3z[1]*x1 + w3z[2]*pf + R.bih[1024 + j];
      float gin = w3n[0]*x0 + w3n[1]*x1 + w3n[2]*pf + R.bih[2048 + j];
      float rr = SIGM(gir + d0 + R.bhh[j]);
      float zz = SIGM(giz + d1 + R.bhh[1024 + j]);
      float nn = tanhf(gin + rr * (d3 + R.bhh[2048 + j]));
      float hv = R.hv[b * 1024 + j];
      R.out[b * 1024 + j] = (1.f - zz) * nn + zz * hv;
    } else if (R.gate == G_GRU) {
      int j = j0 + jj;
      float rr = SIGM(d0 + R.bih[j] + R.bhh[j]);
      float zz = SIGM(d1 + R.bih[1024 + j] + R.bhh[1024 + j]);
      float nn = tanhf(d2 + R.bih[2048 + j] + rr * (d3 + R.bhh[2048 + j]));
      float hv = R.hv[b * 1024 + j];
      float h2 = (1.f - zz) * nn + zz * hv;
      R.out[b * 1024 + j] = h2;
      if (R.out2) R.out2[b * 1024 + j] = h2;
    } else if (R.gate == G_SCR) {
      int j = j0 + jj;
      R.scrw[(size_t)j * 64 + b] = d0;
      R.scrw[(size_t)(1024 + j) * 64 + b] = d1;
      R.scrw[(size_t)(2048 + j) * 64 + b] = d3;
    } else if (R.gate == G_SCRGATE) {
      int j = j0 + jj;
      float ghr = R.scr[(size_t)j * 64 + b] + R.bhh[j];
      float ghz = R.scr[(size_t)(1024 + j) * 64 + b] + R.bhh[1024 + j];
      float ghn = R.scr[(size_t)(2048 + j) * 64 + b] + R.bhh[2048 + j];
      float rr = SIGM(d0 + R.bih[j] + ghr);
      float zz = SIGM(d1 + R.bih[1024 + j] + ghz);
      float nn = tanhf(d2 + R.bih[2048 + j] + rr * ghn);
      float hv = R.hv[b * 1024 + j];
      float h2 = (1.f - zz) * nn + zz * hv;
      R.out[b * 1024 + j] = h2;
      R.out2[b * 2048 + j] = h2;
    } else {
#pragma unroll
      for (int g = 0; g < 3; ++g) {
        int j = j0 + g * 4 + jj;
        float dg = (g == 0) ? d0 : ((g == 1) ? d1 : d2);
        if (j < 1024) R.out[b * 1024 + j] = fmaxf(dg + R.bih[j], 0.f);
      }
    }
  }
}

__global__ __launch_bounds__(256) void score_kernel(
    const float* __restrict__ enc, const float* __restrict__ comb,
    float* __restrict__ sc)
{
  int gw = (blockIdx.x * 256 + threadIdx.x) >> 6;
  int lane = threadIdx.x & 63;
  if (gw >= BB * SS) return;
  int b = gw / SS, s = gw - b * SS;
  const float* e = enc + ((size_t)s * BB + b) * HD;
  const float* q = comb + (size_t)b * 2048;
  float a = 0.f;
#pragma unroll
  for (int i = 0; i < 16; i++) a += e[lane + 64 * i] * q[lane + 64 * i];
  for (int off = 32; off; off >>= 1) a += __shfl_down(a, off);
  if (!lane) sc[b * SS + s] = a;
}

__global__ __launch_bounds__(256) void softmax_amix_kernel(
    const float* __restrict__ sc, const float* __restrict__ enc,
    float* __restrict__ comb, float* __restrict__ attn_out, int t)
{
  __shared__ float w[SS];
  __shared__ float red[256];
  int blk = blockIdx.x; int b = blk / 5, sl = blk - b * 5;
  int tid = threadIdx.x;
  float m = -1e30f;
  for (int s = tid; s < SS; s += 256) { float v = sc[b * SS + s]; w[s] = v; m = fmaxf(m, v); }
  red[tid] = m; __syncthreads();
  for (int o = 128; o; o >>= 1) { if (tid < o) red[tid] = fmaxf(red[tid], red[tid + o]); __syncthreads(); }
  m = red[0]; __syncthreads();
  float sum = 0.f;
  for (int s = tid; s < SS; s += 256) { float e = expf(w[s] - m); w[s] = e; sum += e; }
  red[tid] = sum; __syncthreads();
  for (int o = 128; o; o >>= 1) { if (tid < o) red[tid] += red[tid + o]; __syncthreads(); }
  float inv = 1.f / red[0];
  __syncthreads();
  for (int s = tid; s < SS; s += 256) w[s] *= inv;
  __syncthreads();
  if (sl == 0)
    for (int s = tid; s < SS; s += 256) attn_out[((size_t)b * SS + s) * TT + t] = w[s];
  int j0 = sl * 208; int jl = min(208, 1024 - j0);
  if (tid < jl) {
    int j = j0 + tid; float a = 0.f;
#pragma unroll 4
    for (int s = 0; s < SS; s++) a += w[s] * enc[((size_t)s * BB + b) * HD + j];
    comb[(size_t)b * 2048 + HD + j] = a;
  }
}

__global__ __launch_bounds__(256) void logits_argmax_kernel(
    const float* __restrict__ hfc, const float* __restrict__ fcW,
    const float* __restrict__ fcb, float* __restrict__ outv, int t,
    int* __restrict__ tok)
{
  __shared__ float lg[32];
  int b = blockIdx.x, tid = threadIdx.x;
  int wvv = tid >> 6, lane = tid & 63;
  const float* hb = hfc + (size_t)b * HD;
  for (int v = wvv; v < VV; v += 4) {
    const float* wr = fcW + (size_t)v * HD;
    float a = 0.f;
#pragma unroll
    for (int i = 0; i < 16; i++) a += hb[lane + 64 * i] * wr[lane + 64 * i];
    for (int off = 32; off; off >>= 1) a += __shfl_down(a, off);
    if (!lane) lg[v] = a + fcb[v];
  }
  __syncthreads();
  if (tid == 0) {
    float best = lg[0]; int bi = 0;
    for (int v = 1; v < VV; v++) { if (lg[v] > best) { best = lg[v]; bi = v; } }
    tok[b] = bi;
  }
  if (tid < VV) outv[((size_t)b * TT + t) * VV + tid] = lg[tid];
}

__global__ __launch_bounds__(256) void init_kernel(float* __restrict__ hbufs,
                                                   int* __restrict__ tok)
{
  int i = blockIdx.x * 256 + threadIdx.x;
  if (i < 204800) hbufs[i] = 0.f;
  if (i < BB) tok[i] = 0;
}

__global__ __launch_bounds__(256) void hidcopy_kernel(
    const float* __restrict__ h0, const float* __restrict__ h1,
    float* __restrict__ outh)
{
  int i = blockIdx.x * 256 + threadIdx.x;
  if (i < 51200) { outh[i] = h0[i]; outh[51200 + i] = h1[i]; }
}

// ---------------------------------------------------------------------------
extern "C" void kernel_launch(void* const* d_in, const int* in_sizes, int n_in,
                              void* d_out, int out_size, void* d_ws, size_t ws_size,
                              hipStream_t stream)
{
  const float* x     = (const float*)d_in[0];
  const float* emb   = (const float*)d_in[1];
  const float* eWih0 = (const float*)d_in[2];
  const float* eWhh0 = (const float*)d_in[3];
  const float* ebih0 = (const float*)d_in[4];
  const float* ebhh0 = (const float*)d_in[5];
  const float* eWih1 = (const float*)d_in[6];
  const float* eWhh1 = (const float*)d_in[7];
  const float* ebih1 = (const float*)d_in[8];
  const float* ebhh1 = (const float*)d_in[9];
  const float* dWih  = (const float*)d_in[10];
  const float* dWhh  = (const float*)d_in[11];
  const float* dbih  = (const float*)d_in[12];
  const float* dbhh  = (const float*)d_in[13];
  const float* attnW = (const float*)d_in[14];
  const float* attnB = (const float*)d_in[15];
  const float* fcW   = (const float*)d_in[16];
  const float* fcB   = (const float*)d_in[17];
  float* out = (float*)d_out;

  float* ws = (float*)d_ws;
  float* h0b[2] = { ws,          ws + 51200 };
  float* h1b[2] = { ws + 102400, ws + 153600 };
  float* enc    = ws + 204800;
  float* scr    = enc + (size_t)SS * BB * HD;
  float* comb   = scr + 3072 * 64;
  float* scoreb = comb + BB * 2048;
  float* hfc    = scoreb + BB * SS;
  int*   tok    = (int*)(hfc + BB * HD);

  float* out_vec  = out;
  float* out_hid  = out + BB * TT * VV;
  float* out_attn = out_hid + 2 * BB * HD;

  const float* dWih1 = dWih + (size_t)3072 * 1024;
  const float* dWhh1 = dWhh + (size_t)3072 * 1024;
  const float* dbih1 = dbih + 3072;
  const float* dbhh1 = dbhh + 3072;

  init_kernel<<<800, 256, 0, stream>>>(ws, tok);

  // ---- encoder: single persistent cooperative kernel ----
  EncArgs ea;
  ea.x = x; ea.Wih0 = eWih0; ea.Whh0 = eWhh0; ea.bih0 = ebih0; ea.bhh0 = ebhh0;
  ea.Wih1 = eWih1; ea.Whh1 = eWhh1; ea.bih1 = ebih1; ea.bhh1 = ebhh1;
  ea.h0a = h0b[0]; ea.h0b2 = h0b[1]; ea.h1a = h1b[0]; ea.h1b2 = h1b[1];
  ea.enc = enc;
  void* kargs[] = { (void*)&ea };
  hipLaunchCooperativeKernel((void*)enc_persistent, dim3(256), dim3(1024),
                             kargs, 0, stream);

  Role Z{};

  // ---- decoder (unchanged round-5 structure) ----
  for (int t = 0; t < TT; ++t) {
    float* h0r = h0b[t & 1]; float* h0w = h0b[(t + 1) & 1];
    float* h1r = h1b[t & 1]; float* h1w = h1b[(t + 1) & 1];

    Role DL0 = Z;
    DL0.gatherA = 1; DL0.srcB = h0r; DL0.strB = 1024;
    DL0.Wa = dWih; DL0.wstrA = 1024; DL0.Wb = dWhh;
    DL0.bih = dbih; DL0.bhh = dbhh; DL0.hv = h0r; DL0.out = h0w;
    DL0.K = 2048; DL0.gate = G_GRU; DL0.nsA = 2; DL0.nsB = 3;

    Role GH1 = Z;
    GH1.srcA = h1r; GH1.strA = 1024; GH1.Wa = dWhh1; GH1.wstrA = 1024;
    GH1.scrw = scr; GH1.K = 1024; GH1.gate = G_SCR; GH1.nsA = 3; GH1.nsB = 3;

    fused_gemm<<<512, 256, 0, stream>>>(DL0, GH1, 1, -1, t, x, eWih0, emb, tok);

    Role GI1 = Z;
    GI1.srcA = h0w; GI1.strA = 1024; GI1.Wa = dWih1; GI1.wstrA = 1024;
    GI1.bih = dbih1; GI1.bhh = dbhh1; GI1.hv = h1r; GI1.scr = scr;
    GI1.out = h1w; GI1.out2 = comb;
    GI1.K = 1024; GI1.gate = G_SCRGATE; GI1.nsA = 2; GI1.nsB = 2;

    fused_gemm<<<256, 256, 0, stream>>>(GI1, Z, 0, -1, t, x, eWih0, emb, tok);

    score_kernel<<<(BB * SS * 64 + 255) / 256, 256, 0, stream>>>(enc, comb, scoreb);
    softmax_amix_kernel<<<250, 256, 0, stream>>>(scoreb, enc, comb, out_attn, t);

    Role AF = Z;
    AF.srcA = comb; AF.strA = 2048; AF.Wa = attnW; AF.wstrA = 2048;
    AF.bih = attnB; AF.out = hfc;
    AF.K = 2048; AF.gate = G_RELU; AF.rowsLinear = 1; AF.nsA = 2; AF.nsB = 2;

    fused_gemm<<<86, 256, 0, stream>>>(AF, Z, 0, -1, t, x, eWih0, emb, tok);

    logits_argmax_kernel<<<BB, 256, 0, stream>>>(hfc, fcW, fcB, out_vec, t, tok);
  }

  hidcopy_kernel<<<200, 256, 0, stream>>>(h0b[0], h1b[0], out_hid);
}

// Round 8
// 72639.832 us; speedup vs baseline: 1.5308x; 1.5308x over previous
//
#include <hip/hip_runtime.h>
#include <hip/hip_cooperative_groups.h>
#include <math.h>

namespace cg = cooperative_groups;

#define HD 1024
#define BB 50
#define SS 457
#define TT 32
#define VV 27

#define SSTR 68
#define WSTR 68

#define SIGM(v) (1.f / (1.f + expf(-(v))))

// ===========================================================================
// Persistent cooperative encoder: 256 WGs x 1024 threads, 458 phases.
// Phase p: L0 computes h0[p] = GRU(x_p, h0[p-1]); L1 computes h1[p-1] =
// GRU(h0[p-1], h1[p-2]) -> enc[p-1]. One grid.sync() per phase.
// WG owns 4 j-columns. Decomposition (round-8 redesign, spill/conflict fix):
//   wave wu (0..15) = k-float4 slot within each 64-k window; lane = batch.
//   Per window/thread: 1 ds_read_b128 of h  (LDS row-major [b][68], staged
//   from global with b128 stores, conflict-free-equivalent), 12 wave-uniform
//   weight float4 loads (scalar path, L2-resident per-CU weights), 48 FMAs.
//   Registers ~90 -> no scratch spills (round-7 had VGPR=64 + 148 GB spill
//   writes).  __launch_bounds__(1024,4) -> 128-VGPR budget, 1 block/CU.
// k-reduction: each thread owns unique (k-slot, batch) -> 8 LDS slabs,
// waves 0-7 write, 8-15 add, epilogue sums 8 (deterministic order).
// ===========================================================================
struct EncArgs {
  const float *x, *Wih0, *Whh0, *bih0, *bhh0, *Wih1, *Whh1, *bih1, *bhh1;
  float *h0a, *h0b2, *h1a, *h1b2, *enc;
};

__device__ __forceinline__ float dot4f(float4 w, float4 h, float a) {
  a = fmaf(w.x, h.x, a);
  a = fmaf(w.y, h.y, a);
  a = fmaf(w.z, h.z, a);
  a = fmaf(w.w, h.w, a);
  return a;
}

__global__ __launch_bounds__(1024, 4) void enc_persistent(EncArgs A)
{
  __shared__ __align__(16) float Hs[2][64][SSTR];  // 34.8 KB  [buf][batch][k]
  __shared__ float part[8][16][66];                // 33.8 KB  k-split slabs

  const int tid = threadIdx.x;
  const int wj0 = blockIdx.x * 4;                       // 4 j-cols, <=1020
  const int b   = tid & 63;                             // lane = batch
  const int wu  = __builtin_amdgcn_readfirstlane(tid >> 6);  // wave 0..15
  const int sb  = tid >> 4;                             // staging batch row
  const int sbc = sb < BB ? sb : BB - 1;
  const int sf4 = tid & 15;                             // staging k-f4

  cg::grid_group grid = cg::this_grid();

  float* h0buf[2] = { A.h0a, A.h0b2 };
  float* h1buf[2] = { A.h1a, A.h1b2 };

  auto do_pass = [&](const float* sA, const float* WA,
                     const float* sB, const float* WB,
                     int nwin, int dual) {
    float accR[4]  = {0.f, 0.f, 0.f, 0.f};
    float accZ[4]  = {0.f, 0.f, 0.f, 0.f};
    float accNi[4] = {0.f, 0.f, 0.f, 0.f};
    float accNh[4] = {0.f, 0.f, 0.f, 0.f};

    // prologue: stage window 0 (coalesced global read, b128 LDS store)
    {
      float4 h0g = *(const float4*)(sA + (size_t)sbc * 1024 + (sf4 << 2));
      *(float4*)&Hs[0][sb][sf4 << 2] = h0g;
    }
    __syncthreads();

    for (int win = 0; win < nwin; ++win) {
      const int buf = win & 1;
      const int second = dual && (win >= 16);
      const float* Wm = second ? WB : WA;
      const int ko = ((second ? (win - 16) : win) << 6) + (wu << 2);

      // 12 wave-uniform weight float4 loads (scalar path; L2-hot per CU)
      float4 wv[12];
#pragma unroll
      for (int g = 0; g < 3; ++g)
#pragma unroll
        for (int jl = 0; jl < 4; ++jl)
          wv[g * 4 + jl] =
              *(const float4*)(Wm + (size_t)(g * 1024 + wj0 + jl) * 1024 + ko);

      // prefetch next h window from global (latency hides under FMAs)
      const int nxt = win + 1;
      float4 hg2 = make_float4(0.f, 0.f, 0.f, 0.f);
      if (nxt < nwin) {
        const int sec2 = dual && (nxt >= 16);
        const float* hsrc = sec2 ? sB : sA;
        const int ko2 = (sec2 ? (nxt - 16) : nxt) << 6;
        hg2 = *(const float4*)(hsrc + (size_t)sbc * 1024 + ko2 + (sf4 << 2));
      }

      // this thread's 4 h values (one b128, conflict-free-equivalent)
      const float4 hv = *(const float4*)&Hs[buf][b][wu << 2];

      const bool useNi = dual && (win < 16);
#pragma unroll
      for (int jl = 0; jl < 4; ++jl) {
        accR[jl] = dot4f(wv[jl],     hv, accR[jl]);
        accZ[jl] = dot4f(wv[4 + jl], hv, accZ[jl]);
        if (useNi) accNi[jl] = dot4f(wv[8 + jl], hv, accNi[jl]);
        else       accNh[jl] = dot4f(wv[8 + jl], hv, accNh[jl]);
      }

      // commit next window into other buffer
      if (nxt < nwin) *(float4*)&Hs[buf ^ 1][sb][sf4 << 2] = hg2;
      __syncthreads();
    }

    // deterministic k-slot reduction: waves 0-7 write slabs, 8-15 add
    if (wu < 8) {
#pragma unroll
      for (int jl = 0; jl < 4; ++jl) {
        part[wu][jl * 4 + 0][b] = accR[jl];
        part[wu][jl * 4 + 1][b] = accZ[jl];
        part[wu][jl * 4 + 2][b] = accNi[jl];
        part[wu][jl * 4 + 3][b] = accNh[jl];
      }
    }
    __syncthreads();
    if (wu >= 8) {
#pragma unroll
      for (int jl = 0; jl < 4; ++jl) {
        part[wu - 8][jl * 4 + 0][b] += accR[jl];
        part[wu - 8][jl * 4 + 1][b] += accZ[jl];
        part[wu - 8][jl * 4 + 2][b] += accNi[jl];
        part[wu - 8][jl * 4 + 3][b] += accNh[jl];
      }
    }
    __syncthreads();
  };

  auto sum8 = [&](int r, int bb) {
    float s = part[0][r][bb];
#pragma unroll
    for (int q = 1; q < 8; ++q) s += part[q][r][bb];
    return s;
  };

  for (int p = 0; p <= 457; ++p) {
    const float* h0r = h0buf[(p + 1) & 1];
    float*       h0w = h0buf[p & 1];
    const float* h1r = h1buf[p & 1];
    float*       h1w = h1buf[(p + 1) & 1];

    if (p < 457) {           // L0: h0[p] = GRU(x_p, h0[p-1])
      do_pass(h0r, A.Whh0, nullptr, nullptr, 16, 0);
      if (tid < 200) {
        const int jl = tid / 50, bb = tid - jl * 50;
        const int j = wj0 + jl;
        const float dR  = sum8(jl * 4 + 0, bb);
        const float dZ  = sum8(jl * 4 + 1, bb);
        const float dNh = sum8(jl * 4 + 3, bb);
        const float x0 = A.x[bb * 914 + p];
        const float x1 = A.x[bb * 914 + 457 + p];
        const float pf = (float)p;
        const float* w3r = A.Wih0 + (size_t)j * 3;
        const float* w3z = A.Wih0 + (size_t)(1024 + j) * 3;
        const float* w3n = A.Wih0 + (size_t)(2048 + j) * 3;
        const float gir = w3r[0]*x0 + w3r[1]*x1 + w3r[2]*pf + A.bih0[j];
        const float giz = w3z[0]*x0 + w3z[1]*x1 + w3z[2]*pf + A.bih0[1024 + j];
        const float gin = w3n[0]*x0 + w3n[1]*x1 + w3n[2]*pf + A.bih0[2048 + j];
        const float rr = SIGM(gir + dR + A.bhh0[j]);
        const float zz = SIGM(giz + dZ + A.bhh0[1024 + j]);
        const float nn = tanhf(gin + rr * (dNh + A.bhh0[2048 + j]));
        const float hv0 = h0r[bb * 1024 + j];
        h0w[bb * 1024 + j] = (1.f - zz) * nn + zz * hv0;
      }
      __syncthreads();
    }
    if (p > 0) {             // L1: h1[p-1] = GRU(h0[p-1], h1[p-2]) -> enc
      do_pass(h0r, A.Wih1, h1r, A.Whh1, 32, 1);
      if (tid < 200) {
        const int jl = tid / 50, bb = tid - jl * 50;
        const int j = wj0 + jl;
        const float dR  = sum8(jl * 4 + 0, bb);
        const float dZ  = sum8(jl * 4 + 1, bb);
        const float dNi = sum8(jl * 4 + 2, bb);
        const float dNh = sum8(jl * 4 + 3, bb);
        const float rr = SIGM(dR + A.bih1[j] + A.bhh1[j]);
        const float zz = SIGM(dZ + A.bih1[1024 + j] + A.bhh1[1024 + j]);
        const float nn = tanhf(dNi + A.bih1[2048 + j] + rr * (dNh + A.bhh1[2048 + j]));
        const float hv1 = h1r[bb * 1024 + j];
        const float h2 = (1.f - zz) * nn + zz * hv1;
        h1w[bb * 1024 + j] = h2;
        A.enc[(size_t)(p - 1) * (BB * HD) + bb * 1024 + j] = h2;
      }
      __syncthreads();
    }
    grid.sync();
  }
}

// ===========================================================================
// Decoder kernels (unchanged from round 5/7, which passed)
// ===========================================================================
enum { G_ENC0 = 0, G_GRU = 1, G_SCR = 2, G_SCRGATE = 3, G_RELU = 4 };

struct Role {
  const float* srcA; const float* srcB;
  const float* Wa;   const float* Wb;
  const float* bih;  const float* bhh;
  const float* hv;   const float* scr;
  float* out; float* out2; float* scrw;
  int strA, strB, wstrA, K, gate, rowsLinear, gatherA, nsA, nsB;
};

__global__ __launch_bounds__(256) void fused_gemm(
    Role r0, Role r1, int split, int skipRole, int p,
    const float* __restrict__ x, const float* __restrict__ Wih0,
    const float* __restrict__ emb, const int* __restrict__ tok)
{
  __shared__ __align__(16) float Sk[64][SSTR];
  __shared__ __align__(16) float Wt[12][WSTR];
  __shared__ __align__(16) float part[4][16][4][4][4];

  const int blk = blockIdx.x;
  const int roleId = split ? (blk & 1) : 0;
  if (roleId == skipRole) return;
  const Role& R = roleId ? r1 : r0;
  const int bi2 = split ? (blk >> 1) : blk;
  const int j0 = bi2 * (R.rowsLinear ? 12 : 4);

  const int tid = threadIdx.x;
  const int tx = tid & 3;
  const int ty = (tid >> 2) & 15;
  const int kh = tid >> 6;

  float aR[4] = {0,0,0,0}, aZ[4] = {0,0,0,0}, aN2[4] = {0,0,0,0}, aN3[4] = {0,0,0,0};

  const int nit = R.K >> 6;

  for (int it = 0; it < nit; ++it) {
    const int kw = it << 6;
    const bool second = (R.srcB != nullptr) && (kw >= 1024);
    const int kloc = second ? (kw - 1024) : kw;

    float4 sv[4];
#pragma unroll
    for (int u = 0; u < 4; ++u) {
      int e = tid + (u << 8);
      int bq = e >> 4, f4 = e & 15;
      int bc = bq < BB ? bq : BB - 1;
      const float* rp;
      if (second)         rp = R.srcB + (size_t)bc * R.strB + kloc;
      else if (R.gatherA) rp = emb + (size_t)tok[bc] * HD + kw;
      else                rp = R.srcA + (size_t)bc * R.strA + kw;
      sv[u] = *(const float4*)(rp + (f4 << 2));
    }
    float4 wvq = make_float4(0.f, 0.f, 0.f, 0.f);
    if (tid < 192) {
      int r = tid >> 4, f4 = tid & 15;
      int wrow;
      if (R.rowsLinear) { int j = j0 + r; wrow = j < 1024 ? j : 1023; }
      else { int g = r >> 2, jj = r & 3; int j = j0 + jj; if (j > 1023) j = 1023;
             wrow = g * 1024 + j; }
      const float* wp = second ? (R.Wb + (size_t)wrow * 1024 + kloc)
                               : (R.Wa + (size_t)wrow * R.wstrA + kw);
      wvq = *(const float4*)(wp + (f4 << 2));
    }

    __syncthreads();
#pragma unroll
    for (int u = 0; u < 4; ++u) {
      int e = tid + (u << 8);
      int bq = e >> 4, f4 = e & 15;
      int k = f4 << 2;
      Sk[k + 0][bq] = sv[u].x;
      Sk[k + 1][bq] = sv[u].y;
      Sk[k + 2][bq] = sv[u].z;
      Sk[k + 3][bq] = sv[u].w;
    }
    if (tid < 192) {
      int r = tid >> 4, f4 = tid & 15;
      *(float4*)&Wt[r][f4 << 2] = wvq;
    }
    __syncthreads();

    const bool ns2 = second ? (R.nsB == 2) : (R.nsA == 2);
#define FMA4(A, wc, s) { A[0] = fmaf(wc, s.x, A[0]); A[1] = fmaf(wc, s.y, A[1]); \
                         A[2] = fmaf(wc, s.z, A[2]); A[3] = fmaf(wc, s.w, A[3]); }
#define CBLOCK(AN) \
    _Pragma("unroll") \
    for (int k4 = 0; k4 < 4; ++k4) { \
      const int kk = (kh << 4) + (k4 << 2); \
      float4 w0 = *(const float4*)&Wt[tx][kk]; \
      float4 w1 = *(const float4*)&Wt[4 + tx][kk]; \
      float4 w2 = *(const float4*)&Wt[8 + tx][kk]; \
      float4 s0 = *(const float4*)&Sk[kk + 0][ty << 2]; \
      float4 s1 = *(const float4*)&Sk[kk + 1][ty << 2]; \
      float4 s2 = *(const float4*)&Sk[kk + 2][ty << 2]; \
      float4 s3 = *(const float4*)&Sk[kk + 3][ty << 2]; \
      FMA4(aR, w0.x, s0) FMA4(aR, w0.y, s1) FMA4(aR, w0.z, s2) FMA4(aR, w0.w, s3) \
      FMA4(aZ, w1.x, s0) FMA4(aZ, w1.y, s1) FMA4(aZ, w1.z, s2) FMA4(aZ, w1.w, s3) \
      FMA4(AN, w2.x, s0) FMA4(AN, w2.y, s1) FMA4(AN, w2.z, s2) FMA4(AN, w2.w, s3) \
    }
    if (ns2) { CBLOCK(aN2) } else { CBLOCK(aN3) }
    __syncthreads();
  }

  *(float4*)&part[kh][ty][tx][0][0] = make_float4(aR[0], aR[1], aR[2], aR[3]);
  *(float4*)&part[kh][ty][tx][1][0] = make_float4(aZ[0], aZ[1], aZ[2], aZ[3]);
  *(float4*)&part[kh][ty][tx][2][0] = make_float4(aN2[0], aN2[1], aN2[2], aN2[3]);
  *(float4*)&part[kh][ty][tx][3][0] = make_float4(aN3[0], aN3[1], aN3[2], aN3[3]);
  __syncthreads();

  if (tid < 200) {
    int bq = tid >> 2, jj = tid & 3;
    int py = bq >> 2, pi = bq & 3;
    float d0 = 0.f, d1 = 0.f, d2 = 0.f, d3 = 0.f;
#pragma unroll
    for (int q = 0; q < 4; ++q) {
      d0 += part[q][py][jj][0][pi];
      d1 += part[q][py][jj][1][pi];
      d2 += part[q][py][jj][2][pi];
      d3 += part[q][py][jj][3][pi];
    }
    if (R.gate == G_ENC0) {
      int j = j0 + jj;
      float x0 = x[bq * 914 + p], x1 = x[bq * 914 + 457 + p], pf = (float)p;
      const float* w3r = Wih0 + (size_t)j * 3;
      const float* w3z = Wih0 + (size_t)(1024 + j) * 3;
      const float* w3n = Wih0 + (size_t)(2048 + j) * 3;
      float gir = w3r[0]*x0 + w3r[1]*x1 + w3r[2]*pf + R.bih[j];
      float giz = w3z[0]*x0 + w3z[1]*x1 + w3z[2]*pf + R.bih[1024 + j];
      float gin = w3n[0]*x0 + w3n[1]*x1 + w3n[2]*pf + R.bih[2048 + j];
      float rr = SIGM(gir + d0 + R.bhh[j]);
      float zz = SIGM(giz + d1 + R.bhh[1024 + j]);
      float nn = tanhf(gin + rr * (d3 + R.bhh[2048 + j]));
      float hv = R.hv[bq * 1024 + j];
      R.out[bq * 1024 + j] = (1.f - zz) * nn + zz * hv;
    } else if (R.gate == G_GRU) {
      int j = j0 + jj;
      float rr = SIGM(d0 + R.bih[j] + R.bhh[j]);
      float zz = SIGM(d1 + R.bih[1024 + j] + R.bhh[1024 + j]);
      float nn = tanhf(d2 + R.bih[2048 + j] + rr * (d3 + R.bhh[2048 + j]));
      float hv = R.hv[bq * 1024 + j];
      float h2 = (1.f - zz) * nn + zz * hv;
      R.out[bq * 1024 + j] = h2;
      if (R.out2) R.out2[bq * 1024 + j] = h2;
    } else if (R.gate == G_SCR) {
      int j = j0 + jj;
      R.scrw[(size_t)j * 64 + bq] = d0;
      R.scrw[(size_t)(1024 + j) * 64 + bq] = d1;
      R.scrw[(size_t)(2048 + j) * 64 + bq] = d3;
    } else if (R.gate == G_SCRGATE) {
      int j = j0 + jj;
      float ghr = R.scr[(size_t)j * 64 + bq] + R.bhh[j];
      float ghz = R.scr[(size_t)(1024 + j) * 64 + bq] + R.bhh[1024 + j];
      float ghn = R.scr[(size_t)(2048 + j) * 64 + bq] + R.bhh[2048 + j];
      float rr = SIGM(d0 + R.bih[j] + ghr);
      float zz = SIGM(d1 + R.bih[1024 + j] + ghz);
      float nn = tanhf(d2 + R.bih[2048 + j] + rr * ghn);
      float hv = R.hv[bq * 1024 + j];
      float h2 = (1.f - zz) * nn + zz * hv;
      R.out[bq * 1024 + j] = h2;
      R.out2[bq * 2048 + j] = h2;
    } else {
#pragma unroll
      for (int g = 0; g < 3; ++g) {
        int j = j0 + g * 4 + jj;
        float dg = (g == 0) ? d0 : ((g == 1) ? d1 : d2);
        if (j < 1024) R.out[bq * 1024 + j] = fmaxf(dg + R.bih[j], 0.f);
      }
    }
  }
}

__global__ __launch_bounds__(256) void score_kernel(
    const float* __restrict__ enc, const float* __restrict__ comb,
    float* __restrict__ sc)
{
  int gw = (blockIdx.x * 256 + threadIdx.x) >> 6;
  int lane = threadIdx.x & 63;
  if (gw >= BB * SS) return;
  int b = gw / SS, s = gw - b * SS;
  const float* e = enc + ((size_t)s * BB + b) * HD;
  const float* q = comb + (size_t)b * 2048;
  float a = 0.f;
#pragma unroll
  for (int i = 0; i < 16; i++) a += e[lane + 64 * i] * q[lane + 64 * i];
  for (int off = 32; off; off >>= 1) a += __shfl_down(a, off);
  if (!lane) sc[b * SS + s] = a;
}

__global__ __launch_bounds__(256) void softmax_amix_kernel(
    const float* __restrict__ sc, const float* __restrict__ enc,
    float* __restrict__ comb, float* __restrict__ attn_out, int t)
{
  __shared__ float w[SS];
  __shared__ float red[256];
  int blk = blockIdx.x; int b = blk / 5, sl = blk - b * 5;
  int tid = threadIdx.x;
  float m = -1e30f;
  for (int s = tid; s < SS; s += 256) { float v = sc[b * SS + s]; w[s] = v; m = fmaxf(m, v); }
  red[tid] = m; __syncthreads();
  for (int o = 128; o; o >>= 1) { if (tid < o) red[tid] = fmaxf(red[tid], red[tid + o]); __syncthreads(); }
  m = red[0]; __syncthreads();
  float sum = 0.f;
  for (int s = tid; s < SS; s += 256) { float e = expf(w[s] - m); w[s] = e; sum += e; }
  red[tid] = sum; __syncthreads();
  for (int o = 128; o; o >>= 1) { if (tid < o) red[tid] += red[tid + o]; __syncthreads(); }
  float inv = 1.f / red[0];
  __syncthreads();
  for (int s = tid; s < SS; s += 256) w[s] *= inv;
  __syncthreads();
  if (sl == 0)
    for (int s = tid; s < SS; s += 256) attn_out[((size_t)b * SS + s) * TT + t] = w[s];
  int j0 = sl * 208; int jl = min(208, 1024 - j0);
  if (tid < jl) {
    int j = j0 + tid; float a = 0.f;
#pragma unroll 4
    for (int s = 0; s < SS; s++) a += w[s] * enc[((size_t)s * BB + b) * HD + j];
    comb[(size_t)b * 2048 + HD + j] = a;
  }
}

__global__ __launch_bounds__(256) void logits_argmax_kernel(
    const float* __restrict__ hfc, const float* __restrict__ fcW,
    const float* __restrict__ fcb, float* __restrict__ outv, int t,
    int* __restrict__ tok)
{
  __shared__ float lg[32];
  int b = blockIdx.x, tid = threadIdx.x;
  int wvv = tid >> 6, lane = tid & 63;
  const float* hb = hfc + (size_t)b * HD;
  for (int v = wvv; v < VV; v += 4) {
    const float* wr = fcW + (size_t)v * HD;
    float a = 0.f;
#pragma unroll
    for (int i = 0; i < 16; i++) a += hb[lane + 64 * i] * wr[lane + 64 * i];
    for (int off = 32; off; off >>= 1) a += __shfl_down(a, off);
    if (!lane) lg[v] = a + fcb[v];
  }
  __syncthreads();
  if (tid == 0) {
    float best = lg[0]; int bi = 0;
    for (int v = 1; v < VV; v++) { if (lg[v] > best) { best = lg[v]; bi = v; } }
    tok[b] = bi;
  }
  if (tid < VV) outv[((size_t)b * TT + t) * VV + tid] = lg[tid];
}

__global__ __launch_bounds__(256) void init_kernel(float* __restrict__ hbufs,
                                                   int* __restrict__ tok)
{
  int i = blockIdx.x * 256 + threadIdx.x;
  if (i < 204800) hbufs[i] = 0.f;
  if (i < BB) tok[i] = 0;
}

__global__ __launch_bounds__(256) void hidcopy_kernel(
    const float* __restrict__ h0, const float* __restrict__ h1,
    float* __restrict__ outh)
{
  int i = blockIdx.x * 256 + threadIdx.x;
  if (i < 51200) { outh[i] = h0[i]; outh[51200 + i] = h1[i]; }
}

// ---------------------------------------------------------------------------
extern "C" void kernel_launch(void* const* d_in, const int* in_sizes, int n_in,
                              void* d_out, int out_size, void* d_ws, size_t ws_size,
                              hipStream_t stream)
{
  const float* x     = (const float*)d_in[0];
  const float* emb   = (const float*)d_in[1];
  const float* eWih0 = (const float*)d_in[2];
  const float* eWhh0 = (const float*)d_in[3];
  const float* ebih0 = (const float*)d_in[4];
  const float* ebhh0 = (const float*)d_in[5];
  const float* eWih1 = (const float*)d_in[6];
  const float* eWhh1 = (const float*)d_in[7];
  const float* ebih1 = (const float*)d_in[8];
  const float* ebhh1 = (const float*)d_in[9];
  const float* dWih  = (const float*)d_in[10];
  const float* dWhh  = (const float*)d_in[11];
  const float* dbih  = (const float*)d_in[12];
  const float* dbhh  = (const float*)d_in[13];
  const float* attnW = (const float*)d_in[14];
  const float* attnB = (const float*)d_in[15];
  const float* fcW   = (const float*)d_in[16];
  const float* fcB   = (const float*)d_in[17];
  float* out = (float*)d_out;

  float* ws = (float*)d_ws;
  float* h0b[2] = { ws,          ws + 51200 };
  float* h1b[2] = { ws + 102400, ws + 153600 };
  float* enc    = ws + 204800;
  float* scr    = enc + (size_t)SS * BB * HD;
  float* comb   = scr + 3072 * 64;
  float* scoreb = comb + BB * 2048;
  float* hfc    = scoreb + BB * SS;
  int*   tok    = (int*)(hfc + BB * HD);

  float* out_vec  = out;
  float* out_hid  = out + BB * TT * VV;
  float* out_attn = out_hid + 2 * BB * HD;

  const float* dWih1 = dWih + (size_t)3072 * 1024;
  const float* dWhh1 = dWhh + (size_t)3072 * 1024;
  const float* dbih1 = dbih + 3072;
  const float* dbhh1 = dbhh + 3072;

  init_kernel<<<800, 256, 0, stream>>>(ws, tok);

  // ---- encoder: single persistent cooperative kernel ----
  EncArgs ea;
  ea.x = x; ea.Wih0 = eWih0; ea.Whh0 = eWhh0; ea.bih0 = ebih0; ea.bhh0 = ebhh0;
  ea.Wih1 = eWih1; ea.Whh1 = eWhh1; ea.bih1 = ebih1; ea.bhh1 = ebhh1;
  ea.h0a = h0b[0]; ea.h0b2 = h0b[1]; ea.h1a = h1b[0]; ea.h1b2 = h1b[1];
  ea.enc = enc;
  void* kargs[] = { (void*)&ea };
  hipLaunchCooperativeKernel((void*)enc_persistent, dim3(256), dim3(1024),
                             kargs, 0, stream);

  Role Z{};

  // ---- decoder (unchanged round-5 structure) ----
  for (int t = 0; t < TT; ++t) {
    float* h0r = h0b[t & 1]; float* h0w = h0b[(t + 1) & 1];
    float* h1r = h1b[t & 1]; float* h1w = h1b[(t + 1) & 1];

    Role DL0 = Z;
    DL0.gatherA = 1; DL0.srcB = h0r; DL0.strB = 1024;
    DL0.Wa = dWih; DL0.wstrA = 1024; DL0.Wb = dWhh;
    DL0.bih = dbih; DL0.bhh = dbhh; DL0.hv = h0r; DL0.out = h0w;
    DL0.K = 2048; DL0.gate = G_GRU; DL0.nsA = 2; DL0.nsB = 3;

    Role GH1 = Z;
    GH1.srcA = h1r; GH1.strA = 1024; GH1.Wa = dWhh1; GH1.wstrA = 1024;
    GH1.scrw = scr; GH1.K = 1024; GH1.gate = G_SCR; GH1.nsA = 3; GH1.nsB = 3;

    fused_gemm<<<512, 256, 0, stream>>>(DL0, GH1, 1, -1, t, x, eWih0, emb, tok);

    Role GI1 = Z;
    GI1.srcA = h0w; GI1.strA = 1024; GI1.Wa = dWih1; GI1.wstrA = 1024;
    GI1.bih = dbih1; GI1.bhh = dbhh1; GI1.hv = h1r; GI1.scr = scr;
    GI1.out = h1w; GI1.out2 = comb;
    GI1.K = 1024; GI1.gate = G_SCRGATE; GI1.nsA = 2; GI1.nsB = 2;

    fused_gemm<<<256, 256, 0, stream>>>(GI1, Z, 0, -1, t, x, eWih0, emb, tok);

    score_kernel<<<(BB * SS * 64 + 255) / 256, 256, 0, stream>>>(enc, comb, scoreb);
    softmax_amix_kernel<<<250, 256, 0, stream>>>(scoreb, enc, comb, out_attn, t);

    Role AF = Z;
    AF.srcA = comb; AF.strA = 2048; AF.Wa = attnW; AF.wstrA = 2048;
    AF.bih = attnB; AF.out = hfc;
    AF.K = 2048; AF.gate = G_RELU; AF.rowsLinear = 1; AF.nsA = 2; AF.nsB = 2;

    fused_gemm<<<86, 256, 0, stream>>>(AF, Z, 0, -1, t, x, eWih0, emb, tok);

    logits_argmax_kernel<<<BB, 256, 0, stream>>>(hfc, fcW, fcB, out_vec, t, tok);
  }

  hidcopy_kernel<<<200, 256, 0, stream>>>(h0b[0], h1b[0], out_hid);
}